// Round 11
// baseline (121.766 us; speedup 1.0000x reference)
//
#include <hip/hip_runtime.h>
#include <math.h>

#define BB 8
#define TT 4096
#define DD 2048
#define THREADS 512           // 8 waves; wave w owns batch row b=w
#define NT 8                  // t-steps per block
#define NBLK (TT / NT)        // 512 blocks -> 1 resident/CU (LDS-bound), 2 sequential
#define SMEM_BYTES ((2 * (BB * DD + DD)) * 4)   // 147456 B: 2 x-tiles + 2 pos rows

typedef float v4f __attribute__((ext_vector_type(4)));

__device__ __forceinline__ float gelu_fast(float x) {
    // gelu(x) = x * sigmoid(2c*(x + 0.044715 x^3)); saturates correctly.
    const float c1 = 1.5957691216057308f;    // 2*sqrt(2/pi)
    const float c2 = 0.07135481282556483f;   // 2c*0.044715
    float e = __expf(-x * fmaf(c2, x * x, c1));
    return x * __builtin_amdgcn_rcpf(1.0f + e);
}

// async global->LDS, 16B per lane; LDS dest is wave-uniform base + lane*16
__device__ __forceinline__ void gl2lds(const float* g, float* l) {
    __builtin_amdgcn_global_load_lds(
        (const __attribute__((address_space(1))) void*)g,
        (__attribute__((address_space(3))) void*)l, 16, 0, 0);
}

__global__ __launch_bounds__(THREADS, 2) void gelu275_fused(
    const float* __restrict__ x,          // [B,T,D]
    const float* __restrict__ log_k_pos,  // [1]
    const float* __restrict__ pos_buf,    // [T,D]
    const float* __restrict__ pos_facil,  // [T]
    float* __restrict__ out)              // [B,T,D]
{
    extern __shared__ __align__(16) float smem[];
    // layout: xbuf0[8][2048] | xbuf1[8][2048] | pbuf0[2048] | pbuf1[2048]
    float* const xbuf0 = smem;
    float* const xbuf1 = smem + BB * DD;
    float* const pbuf0 = smem + 2 * BB * DD;
    float* const pbuf1 = pbuf0 + DD;
    __shared__ float s_red[2][17];        // parity-double-buffered partials

    const int tid  = threadIdx.x;
    const int lane = tid & 63;
    const int wave = tid >> 6;            // == batch row b
    const int t0   = blockIdx.x * NT;
    const int base = lane * 4;

    const float kp = fminf(fmaxf(__expf(log_k_pos[0]), 0.01f), 5.0f);
    // hoist facil loads (uniform address -> s_load, lgkm not vmcnt) so the
    // per-step VMEM stream is exactly 9 gl2lds + 8 stores per wave
    float pfv[NT];
#pragma unroll
    for (int i = 0; i < NT; ++i) pfv[i] = pos_facil[t0 + i];

    // prologue: stage tile 0 into buffer 0 (9 global_load_lds per wave)
    {
        const float* xrow = x + ((size_t)wave * TT + t0) * DD;
#pragma unroll
        for (int c = 0; c < 8; ++c)
            gl2lds(xrow + c * 256 + base, xbuf0 + wave * DD + c * 256);
        gl2lds(pos_buf + (size_t)t0 * DD + wave * 256 + base,
               pbuf0 + wave * 256);
    }

#pragma unroll
    for (int i = 0; i < NT; ++i) {
        float* const xb = (i & 1) ? xbuf1 : xbuf0;
        float* const pb = (i & 1) ? pbuf1 : pbuf0;

        // --- issue tile i+1 prefetch FIRST, before waiting for tile i.
        // Target buffer was freed by step i-1's mid-barrier (lgkm drain
        // covers all ds_reads of it), so this is race-free — and the read
        // queue never drains: loads(i+1) sit behind loads(i) while we wait.
        if (i + 1 < NT) {
            float* const xn = (i & 1) ? xbuf0 : xbuf1;
            float* const pn = (i & 1) ? pbuf0 : pbuf1;
            const float* xrow = x + ((size_t)wave * TT + (t0 + i + 1)) * DD;
#pragma unroll
            for (int c = 0; c < 8; ++c)
                gl2lds(xrow + c * 256 + base, xn + wave * DD + c * 256);
            gl2lds(pos_buf + (size_t)(t0 + i + 1) * DD + wave * 256 + base,
                   pn + wave * 256);
        }

        // --- counted wait: retire ONLY tile i's 9 loads (oldest in the
        // queue); stores(i-1) [8] and loads(i+1) [9] stay in flight.
        if (i == 0)           { asm volatile("s_waitcnt vmcnt(9)"  ::: "memory"); }
        else if (i == NT - 1) { asm volatile("s_waitcnt vmcnt(8)"  ::: "memory"); }
        else                  { asm volatile("s_waitcnt vmcnt(17)" ::: "memory"); }
        __builtin_amdgcn_s_barrier();
        asm volatile("" ::: "memory");

        // --- compute: read own row + pos from LDS, gelu, partials
        v4f Y[8];
        float dot = 0.f, yn2 = 0.f, pn2 = 0.f;
#pragma unroll
        for (int c = 0; c < 8; ++c) {
            v4f v       = *(const v4f*)(xb + wave * DD + c * 256 + base);
            const v4f p = *(const v4f*)(pb + c * 256 + base);
            v.x = gelu_fast(v.x); v.y = gelu_fast(v.y);
            v.z = gelu_fast(v.z); v.w = gelu_fast(v.w);
            Y[c] = v;
            dot += v.x * p.x + v.y * p.y + v.z * p.z + v.w * p.w;
            yn2 += v.x * v.x + v.y * v.y + v.z * v.z + v.w * v.w;
            pn2 += p.x * p.x + p.y * p.y + p.z * p.z + p.w * p.w;
        }

        // --- wave butterfly (3 values x 6 rounds), cross-wave via LDS
#pragma unroll
        for (int off = 32; off; off >>= 1) {
            dot += __shfl_xor(dot, off);
            yn2 += __shfl_xor(yn2, off);
            pn2 += __shfl_xor(pn2, off);
        }
        if (lane == 0) {
            s_red[i & 1][wave]     = dot;
            s_red[i & 1][8 + wave] = yn2;
            if (wave == 0) s_red[i & 1][16] = pn2;
        }
        // LDS-only drain + raw barrier: prefetched tile stays in flight.
        // This barrier also marks buf[i&1] dead -> step i+1 may overwrite.
        asm volatile("s_waitcnt lgkmcnt(0)" ::: "memory");
        __builtin_amdgcn_s_barrier();
        asm volatile("" ::: "memory");

        // --- gate from the 17 LDS scalars (redundant per thread)
        const float pnn = fmaxf(sqrtf(s_red[i & 1][16]), 1e-12f);
        float simsum = 0.f, simw = 0.f;
#pragma unroll
        for (int bb = 0; bb < BB; ++bb) {
            const float s = s_red[i & 1][bb] *
                __builtin_amdgcn_rcpf(
                    fmaxf(sqrtf(s_red[i & 1][8 + bb]), 1e-12f) * pnn);
            simsum += s;
            if (bb == wave) simw = s;
        }
        const bool  fire  = (simsum * 0.125f) > 0.85f;
        const float pf    = pfv[i];
        const float facil = fire ? fminf(pf * 2.0f, 16.0f) : pf;
        const float g     = fminf(1.0f + kp * (facil - 1.0f) * simw, 8.0f);

        // --- gated store of this wave's row (exactly 8 VMEM stores/wave)
        float* orow = out + ((size_t)wave * TT + (t0 + i)) * DD + base;
#pragma unroll
        for (int c = 0; c < 8; ++c) {
            v4f o = Y[c];
            o.x *= g; o.y *= g; o.z *= g; o.w *= g;
            *(v4f*)(orow + c * 256) = o;
        }
    }
}

extern "C" void kernel_launch(void* const* d_in, const int* in_sizes, int n_in,
                              void* d_out, int out_size, void* d_ws, size_t ws_size,
                              hipStream_t stream) {
    const float* x          = (const float*)d_in[0];
    const float* log_k_pos  = (const float*)d_in[1];
    const float* pos_buf    = (const float*)d_in[2];
    const float* pos_facil  = (const float*)d_in[3];
    float* out              = (float*)d_out;

    // allow >64KB dynamic LDS (idempotent; set on first (non-captured) call)
    (void)hipFuncSetAttribute((const void*)gelu275_fused,
                              hipFuncAttributeMaxDynamicSharedMemorySize,
                              SMEM_BYTES);

    dim3 grid(NBLK);
    dim3 block(THREADS);
    gelu275_fused<<<grid, block, SMEM_BYTES, stream>>>(
        x, log_k_pos, pos_buf, pos_facil, out);
}

// Round 12
// 119.677 us; speedup vs baseline: 1.0174x; 1.0174x over previous
//
#include <hip/hip_runtime.h>
#include <math.h>

#define BB 8
#define TT 4096
#define DD 2048
#define HALF 1024             // floats per half-row
#define THREADS 512           // 8 waves; wave w owns batch row b=w
#define NT 8                  // t-steps per block
#define NBLK (TT / NT)        // 512 blocks -> 2 resident/CU (72KB LDS each)
#define NG (NT * 2)           // half-steps per block
#define SMEM_BYTES ((2 * BB * HALF + 2 * HALF) * 4)   // 73728 B

typedef float v4f __attribute__((ext_vector_type(4)));

__device__ __forceinline__ float gelu_fast(float x) {
    // gelu(x) = x * sigmoid(2c*(x + 0.044715 x^3)); saturates correctly.
    const float c1 = 1.5957691216057308f;    // 2*sqrt(2/pi)
    const float c2 = 0.07135481282556483f;   // 2c*0.044715
    float e = __expf(-x * fmaf(c2, x * x, c1));
    return x * __builtin_amdgcn_rcpf(1.0f + e);
}

__device__ __forceinline__ void gl2lds16(const float* g, float* l) {
    __builtin_amdgcn_global_load_lds(
        (const __attribute__((address_space(1))) void*)g,
        (__attribute__((address_space(3))) void*)l, 16, 0, 0);
}
__device__ __forceinline__ void gl2lds4(const float* g, float* l) {
    __builtin_amdgcn_global_load_lds(
        (const __attribute__((address_space(1))) void*)g,
        (__attribute__((address_space(3))) void*)l, 4, 0, 0);
}

__global__ __launch_bounds__(THREADS, 4) void gelu275_fused(
    const float* __restrict__ x,          // [B,T,D]
    const float* __restrict__ log_k_pos,  // [1]
    const float* __restrict__ pos_buf,    // [T,D]
    const float* __restrict__ pos_facil,  // [T]
    float* __restrict__ out)              // [B,T,D]
{
    extern __shared__ __align__(16) float smem[];
    // layout: xbuf0[8][1024] | xbuf1[8][1024] | pbuf0[1024] | pbuf1[1024]
    float* const xbuf0 = smem;
    float* const xbuf1 = smem + BB * HALF;
    float* const pbuf0 = smem + 2 * BB * HALF;
    float* const pbuf1 = pbuf0 + HALF;
    __shared__ float s_red[17];           // single-buffered (barrier-protected)

    const int tid  = threadIdx.x;
    const int lane = tid & 63;
    const int wave = tid >> 6;            // == batch row b
    const int t0   = blockIdx.x * NT;
    const int base = lane * 4;

    const float kp = fminf(fmaxf(__expf(log_k_pos[0]), 0.01f), 5.0f);
    // uniform-address scalar loads (lgkm, not vmcnt) -> ledger stays exact
    float pfv[NT];
#pragma unroll
    for (int i = 0; i < NT; ++i) pfv[i] = pos_facil[t0 + i];

    const float* xrow = x       + ((size_t)wave * TT + t0) * DD;
    const float* prow = pos_buf + (size_t)t0 * DD;
    float*       orow = out     + ((size_t)wave * TT + t0) * DD;

    // prologue: issue half g=0 (t0, h=0): 4 x-loads + 2 pos-loads per wave
    {
#pragma unroll
        for (int c = 0; c < 4; ++c)
            gl2lds16(xrow + c * 256 + base, xbuf0 + wave * HALF + c * 256);
        gl2lds4(prow + wave * 128 + lane,      pbuf0 + wave * 128);
        gl2lds4(prow + wave * 128 + 64 + lane, pbuf0 + wave * 128 + 64);
    }

    v4f Y[8];                             // full-row y, filled across 2 halves
    float dot = 0.f, yn2 = 0.f, pn2 = 0.f;

#pragma unroll
    for (int g = 0; g < NG; ++g) {
        const int tloc = g >> 1;
        const int h    = g & 1;
        float* const xc = h ? xbuf1 : xbuf0;
        float* const pc = h ? pbuf1 : pbuf0;

        // 1) issue NEXT half's 6 loads (its buffer was freed by the exit
        //    barrier of half g-1; read queue never empties)
        if (g + 1 < NG) {
            const int tn = (g + 1) >> 1;
            const int hn = (g + 1) & 1;
            float* const xn = hn ? xbuf1 : xbuf0;
            float* const pn = hn ? pbuf1 : pbuf0;
            const float* xs = xrow + (size_t)tn * DD + hn * HALF;
            const float* pp = prow + (size_t)tn * DD + hn * HALF;
#pragma unroll
            for (int c = 0; c < 4; ++c)
                gl2lds16(xs + c * 256 + base, xn + wave * HALF + c * 256);
            gl2lds4(pp + wave * 128 + lane,      pn + wave * 128);
            gl2lds4(pp + wave * 128 + 64 + lane, pn + wave * 128 + 64);
        }

        // 2) counted wait for THIS half's 6 loads (issued one half-step ago).
        //    In-order vmcnt decrement => immediate = #ops issued after them:
        //    h0 steady: 8 stores + 6 next-loads = 14; h1: 6; first: 6; last: 0.
        if (g == 0)           { asm volatile("s_waitcnt vmcnt(6)"  ::: "memory"); }
        else if (g == NG - 1) { asm volatile("s_waitcnt vmcnt(0)"  ::: "memory"); }
        else if (h == 0)      { asm volatile("s_waitcnt vmcnt(14)" ::: "memory"); }
        else                  { asm volatile("s_waitcnt vmcnt(6)"  ::: "memory"); }
        __builtin_amdgcn_s_barrier();
        asm volatile("" ::: "memory");

        // 3) compute this half from LDS (own row + shared pos half)
        if (h == 0) { dot = 0.f; yn2 = 0.f; pn2 = 0.f; }
#pragma unroll
        for (int c = 0; c < 4; ++c) {
            v4f v       = *(const v4f*)(xc + wave * HALF + c * 256 + base);
            const v4f p = *(const v4f*)(pc + c * 256 + base);
            v.x = gelu_fast(v.x); v.y = gelu_fast(v.y);
            v.z = gelu_fast(v.z); v.w = gelu_fast(v.w);
            Y[h * 4 + c] = v;
            dot += v.x * p.x + v.y * p.y + v.z * p.z + v.w * p.w;
            yn2 += v.x * v.x + v.y * v.y + v.z * v.z + v.w * v.w;
            pn2 += p.x * p.x + p.y * p.y + p.z * p.z + p.w * p.w;
        }

        // 4) after h1: full-row butterfly reduce, publish to LDS
        if (h == 1) {
#pragma unroll
            for (int off = 32; off; off >>= 1) {
                dot += __shfl_xor(dot, off);
                yn2 += __shfl_xor(yn2, off);
                pn2 += __shfl_xor(pn2, off);
            }
            if (lane == 0) {
                s_red[wave]     = dot;
                s_red[8 + wave] = yn2;
                if (wave == 0) s_red[16] = pn2;
            }
        }

        // 5) exit barrier: LDS-only drain keeps prefetch in flight; frees
        //    buf[g&1] for reuse and (h1) makes s_red visible
        asm volatile("s_waitcnt lgkmcnt(0)" ::: "memory");
        __builtin_amdgcn_s_barrier();
        asm volatile("" ::: "memory");

        // 6) after h1: gate + 8 stores of the full row
        if (h == 1) {
            const float pnn = fmaxf(sqrtf(s_red[16]), 1e-12f);
            float simsum = 0.f, simw = 0.f;
#pragma unroll
            for (int bb = 0; bb < BB; ++bb) {
                const float s = s_red[bb] *
                    __builtin_amdgcn_rcpf(
                        fmaxf(sqrtf(s_red[8 + bb]), 1e-12f) * pnn);
                simsum += s;
                if (bb == wave) simw = s;
            }
            const bool  fire  = (simsum * 0.125f) > 0.85f;
            const float pf    = pfv[tloc];
            const float facil = fire ? fminf(pf * 2.0f, 16.0f) : pf;
            const float gt    = fminf(1.0f + kp * (facil - 1.0f) * simw, 8.0f);

            float* o = orow + (size_t)tloc * DD;
#pragma unroll
            for (int k = 0; k < 8; ++k) {
                v4f ov = Y[k];
                ov.x *= gt; ov.y *= gt; ov.z *= gt; ov.w *= gt;
                *(v4f*)(o + (k >> 2) * HALF + (k & 3) * 256 + base) = ov;
            }
        }
    }
}

extern "C" void kernel_launch(void* const* d_in, const int* in_sizes, int n_in,
                              void* d_out, int out_size, void* d_ws, size_t ws_size,
                              hipStream_t stream) {
    const float* x          = (const float*)d_in[0];
    const float* log_k_pos  = (const float*)d_in[1];
    const float* pos_buf    = (const float*)d_in[2];
    const float* pos_facil  = (const float*)d_in[3];
    float* out              = (float*)d_out;

    // allow >64KB dynamic LDS (idempotent; set on first (non-captured) call)
    (void)hipFuncSetAttribute((const void*)gelu275_fused,
                              hipFuncAttributeMaxDynamicSharedMemorySize,
                              SMEM_BYTES);

    dim3 grid(NBLK);
    dim3 block(THREADS);
    gelu275_fused<<<grid, block, SMEM_BYTES, stream>>>(
        x, log_k_pos, pos_buf, pos_facil, out);
}